// Round 19
// baseline (388.006 us; speedup 1.0000x reference)
//
#include <hip/hip_runtime.h>
#include <stdint.h>

#define T_SEQ 2048
#define DMODEL 4096
#define DQKV 6144          // fused Q(4096) + K(1024) + V(1024) output width
#define KOFF 4096          // K column offset in QKV
#define VOFF 5120          // V column offset in QKV
#define DHEAD 128
#define NHEADS 32
#define NKV 8

typedef unsigned short u16;
typedef __attribute__((ext_vector_type(8))) __bf16 bf16x8;
typedef __attribute__((ext_vector_type(4))) float f32x4;

__device__ __forceinline__ u16 f2bf(float f) {
    uint32_t u = __builtin_bit_cast(uint32_t, f);
    u += 0x7FFFu + ((u >> 16) & 1u);
    return (u16)(u >> 16);
}
__device__ __forceinline__ u16 f2bf_trunc(float f) {   // cheap truncation (P-values only)
    return (u16)(__builtin_bit_cast(uint32_t, f) >> 16);
}
__device__ __forceinline__ float bf2f(u16 b) {
    return __builtin_bit_cast(float, (uint32_t)b << 16);
}

__device__ __forceinline__ void gload_lds16(const u16* g, u16* l) {
    __builtin_amdgcn_global_load_lds((const __attribute__((address_space(1))) uint32_t*)g,
                                     (__attribute__((address_space(3))) uint32_t*)l, 16, 0, 0);
}

// =================================================================================
// prep kernel: fuses f32->bf16 convert of resid (cvt), all 4 weight transpose-
// converts (tcvt), and the RoPE cos/sin table build. Flat grid, branch on bid.
// =================================================================================
__global__ void prep_kernel(const float* __restrict__ resid,
                            const float* __restrict__ Wq, const float* __restrict__ Wk,
                            const float* __restrict__ Wv, const float* __restrict__ Wo,
                            u16* __restrict__ Xb,
                            u16* __restrict__ WqT, u16* __restrict__ WkT,
                            u16* __restrict__ WvT, u16* __restrict__ WoT,
                            float* __restrict__ cosT, float* __restrict__ sinT) {
    __shared__ float tile[32][33];
    int bid = blockIdx.x, tid = threadIdx.x;
    if (bid < 2048) {
        int n4 = T_SEQ * DMODEL / 4;
        int i = bid * 256 + tid;
        int stride = 2048 * 256;
        for (; i < n4; i += stride) {
            float4 v = ((const float4*)resid)[i];
            ushort4 o;
            o.x = f2bf(v.x); o.y = f2bf(v.y); o.z = f2bf(v.z); o.w = f2bf(v.w);
            ((ushort4*)Xb)[i] = o;
        }
    } else if (bid < 43008) {
        int b = bid - 2048;
        const float* in; u16* out; int C, s;
        if (b < 16384)      { in = Wq; out = WqT; C = DMODEL; s = b; }
        else if (b < 20480) { in = Wk; out = WkT; C = 1024;   s = b - 16384; }
        else if (b < 24576) { in = Wv; out = WvT; C = 1024;   s = b - 20480; }
        else                { in = Wo; out = WoT; C = DMODEL; s = b - 24576; }
        int ntx = C / 32;
        int c0 = (s % ntx) * 32, r0 = (s / ntx) * 32;
        int tx = tid & 31, ty = tid >> 5;  // 32 x 8
#pragma unroll
        for (int i = 0; i < 32; i += 8)
            tile[ty + i][tx] = in[(size_t)(r0 + ty + i) * C + c0 + tx];
        __syncthreads();
#pragma unroll
        for (int i = 0; i < 32; i += 8)
            out[(size_t)(c0 + ty + i) * DMODEL + r0 + tx] = f2bf(tile[tx][ty + i]);
    } else {
        int local = (bid - 43008) * 256 + tid;
        int t = local >> 6, d = local & 63;
        const float TWO_PI = 6.283185307179586f;
        float fidx = (float)d * (1.0f / 64.0f);
        float freq = (1.0f / TWO_PI) * powf(500000.0f, -fidx);
        const float factor = 32.0f, lo = 1.0f, hi = 4.0f, L0 = 8192.0f;
        float fl = lo / L0, fh = hi / L0;
        float smooth = fminf(fmaxf((L0 * freq - lo) / (hi - lo), 0.0f), 1.0f);
        float fs = (1.0f - smooth) * (freq / factor) + smooth * freq;
        float fr = (freq < fl) ? (freq / factor) : freq;
        if (freq >= fl && freq <= fh) fr = fs;
        float ang = TWO_PI * (float)t * fr;
        cosT[t * 64 + d] = cosf(ang);
        sinT[t * 64 + d] = sinf(ang);
    }
}

// =================================================================================
// ropevt kernel: fuses in-place RoPE on fused QKV (Q heads pre-scaled into log2
// domain, K heads plain) with the V-slice transpose.
// =================================================================================
__global__ void ropevt_kernel(u16* __restrict__ QKV, u16* __restrict__ Vt,
                              const float* __restrict__ cosT, const float* __restrict__ sinT) {
    __shared__ u16 tile[32][33];
    int bid = blockIdx.x, tid = threadIdx.x;
    if (bid < 20480) {
        const float QSCL = 0.08838834764831845f * 1.4426950408889634f;
        int i = bid * 256 + tid;
        int d = i & 63;
        int h = (i >> 6) % 40;
        int t = i / (40 * 64);
        int col = (h < 32) ? (h * 128 + d) : (KOFF + (h - 32) * 128 + d);
        size_t base = (size_t)t * DQKV + col;
        float x0 = bf2f(QKV[base]), x1 = bf2f(QKV[base + 64]);
        float c = cosT[t * 64 + d], s = sinT[t * 64 + d];
        float y0 = x0 * c - x1 * s;
        float y1 = x1 * c + x0 * s;
        if (h < 32) { y0 *= QSCL; y1 *= QSCL; }
        QKV[base] = f2bf(y0);
        QKV[base + 64] = f2bf(y1);
    } else {
        int s = bid - 20480;
        int t0 = (s & 63) * 32, d0 = (s >> 6) * 32;
        int tx = tid & 31, ty = tid >> 5;  // 32 x 8
#pragma unroll
        for (int i = 0; i < 32; i += 8)
            tile[ty + i][tx] = QKV[(size_t)(t0 + ty + i) * DQKV + VOFF + d0 + tx];
        __syncthreads();
#pragma unroll
        for (int i = 0; i < 32; i += 8)
            Vt[(size_t)(d0 + ty + i) * T_SEQ + t0 + tx] = tile[tx][ty + i];
    }
}

// =================================================================================
// GEMM, 3-barrier halves + compiler-counted LDS waits (verified R18): C = A * Bt^T
// =================================================================================
template<int BM, int BN, int WR, int WC, int E>
__launch_bounds__(512, 1)
__global__ void gemm8p(const u16* __restrict__ A, const u16* __restrict__ Bt,
                       void* __restrict__ Cout, int M, int N, int K, int f32out) {
    constexpr int WM = BM / WR, WN = BN / WC;      // per-wave output tile
    constexpr int FM = WM / 16, FN = WN / 16;      // fragments per wave
    constexpr int FMH = FM / 2, FNH = FN / 2;      // fragments per quadrant
    constexpr int NCH = (BM + BN) / 64;            // 64-row stage chunks per K-tile
    constexpr int TILE = (BM + BN) * 64;           // u16 per LDS buffer
    static_assert(E * 64 <= BM, "E-region must stay within A rows");
    extern __shared__ u16 lds[];

    int tid = threadIdx.x;
    int lane = tid & 63, wid = tid >> 6;
    int l15 = lane & 15, lg = lane >> 4;
    int wm0 = (wid / WC) * WM, wn0 = (wid % WC) * WN;
    int m0 = blockIdx.y * BM, n0 = blockIdx.x * BN;
    int rsw = l15 & 7;                             // read-side swizzle = row & 7
    int rl = tid >> 3, cc = tid & 7;
    int scc = cc ^ (rl & 7);                       // source-side pre-swizzle (involution)
    const u16* Ag = A + (size_t)(m0 + rl) * K + scc * 8;
    const u16* Bg = Bt + (size_t)(n0 + rl) * K + scc * 8;
    int niters = K >> 7;

    f32x4 acc[FM][FN] = {};
    bf16x8 aQ0[FMH][2], aQ1[FMH][2];               // A-fragment sets (quad-halves 0/1)
    bf16x8 bQ0[FNH][2], bQ1[FNH][2];               // B-fragment sets

    auto stg = [&](int buf, int t, int clo, int chi) {
#pragma unroll
        for (int c = 0; c < NCH; ++c)
            if (c >= clo && c < chi) {
                const u16* g = (c * 64 < BM) ? (Ag + (size_t)(c * 64) * K + (size_t)t * 64)
                                             : (Bg + (size_t)(c * 64 - BM) * K + (size_t)t * 64);
                gload_lds16(g, lds + buf * TILE + c * 4096 + tid * 8);
            }
    };

#define RDA(buf, qm, DST) { _Pragma("unroll") for (int mi = 0; mi < FMH; ++mi) { \
    int row = wm0 + (qm) * (WM / 2) + mi * 16 + l15; \
    _Pragma("unroll") for (int h = 0; h < 2; ++h) \
        DST[mi][h] = *(const bf16x8*)&lds[(buf) * TILE + row * 64 + (((h * 4 + lg) ^ rsw) * 8)]; } }
#define RDB(buf, qn, DST) { _Pragma("unroll") for (int ni = 0; ni < FNH; ++ni) { \
    int row = wn0 + (qn) * (WN / 2) + ni * 16 + l15; \
    _Pragma("unroll") for (int h = 0; h < 2; ++h) \
        DST[ni][h] = *(const bf16x8*)&lds[(buf) * TILE + BM * 64 + row * 64 + (((h * 4 + lg) ^ rsw) * 8)]; } }
#define MMQ(AR, BR, qm, qn) { _Pragma("unroll") for (int mi = 0; mi < FMH; ++mi) \
    _Pragma("unroll") for (int ni = 0; ni < FNH; ++ni) { \
    acc[(qm)*FMH+mi][(qn)*FNH+ni] = __builtin_amdgcn_mfma_f32_16x16x32_bf16(AR[mi][0], BR[ni][0], acc[(qm)*FMH+mi][(qn)*FNH+ni], 0, 0, 0); \
    acc[(qm)*FMH+mi][(qn)*FNH+ni] = __builtin_amdgcn_mfma_f32_16x16x32_bf16(AR[mi][1], BR[ni][1], acc[(qm)*FMH+mi][(qn)*FNH+ni], 0, 0, 0); } }
#define SB0     __builtin_amdgcn_sched_barrier(0)
#define BAR     __builtin_amdgcn_s_barrier()
#define PRIO1   __builtin_amdgcn_s_setprio(1)
#define PRIO0   __builtin_amdgcn_s_setprio(0)
#define FENCE_E asm volatile("s_waitcnt vmcnt(%0)" :: "i"(E) : "memory")
#define FENCE_0 asm volatile("s_waitcnt vmcnt(0)" ::: "memory")

    // Prologue: tile0 -> buf0 (all chunks), tile1 -> buf1 (first E chunks).
    stg(0, 0, 0, NCH);
    stg(1, 1, 0, E);
    FENCE_E; SB0; BAR;
    RDA(0, 0, aQ0); RDB(0, 0, bQ0);   // tile0 quad0 operands (buf0 complete)

    for (int it = 0; it < niters; ++it) {
        int t0 = 2 * it, t1 = t0 + 1;
        bool last = (it == niters - 1);
        // ---- half 1: tile t0 (buf0); stage t1 rest (buf1) ----
        RDB(0, 1, bQ1); RDA(0, 1, aQ1);
        stg(1, t1, E, NCH);
        SB0; BAR;
        PRIO1; MMQ(aQ0, bQ0, 0, 0); MMQ(aQ0, bQ1, 0, 1); MMQ(aQ1, bQ1, 1, 1); PRIO0;
        SB0; BAR;
        if (!last) stg(0, t0 + 2, 0, E);     // buf0 A: aQ0/aQ1 drained by MFMA waits before BAR above
        SB0;
        PRIO1; MMQ(aQ1, bQ0, 1, 0); PRIO0;
        if (last) { FENCE_0; } else { FENCE_E; }
        SB0; BAR;
        RDA(1, 0, aQ0); RDB(1, 0, bQ0);      // buf1 fully staged (fence+BAR)
        // ---- half 2: tile t1 (buf1); stage t0+2 rest (buf0) ----
        RDB(1, 1, bQ1); RDA(1, 1, aQ1);
        if (!last) stg(0, t0 + 2, E, NCH);   // buf0 B: bQ0/bQ1 drained >=1 BAR ago
        SB0; BAR;
        PRIO1; MMQ(aQ0, bQ0, 0, 0); MMQ(aQ0, bQ1, 0, 1); MMQ(aQ1, bQ1, 1, 1); PRIO0;
        SB0; BAR;
        if (!last) stg(1, t1 + 2, 0, E);     // buf1 A: reads drained before BAR above
        SB0;
        PRIO1; MMQ(aQ1, bQ0, 1, 0); PRIO0;
        if (!last) {
            FENCE_E; SB0; BAR;
            RDA(0, 0, aQ0); RDB(0, 0, bQ0);  // next tile quad0 (buf0 fully staged)
        }
    }
#undef RDA
#undef RDB
#undef MMQ
#undef SB0
#undef BAR
#undef PRIO1
#undef PRIO0
#undef FENCE_E
#undef FENCE_0

#pragma unroll
    for (int fm = 0; fm < FM; ++fm)
#pragma unroll
        for (int fn = 0; fn < FN; ++fn)
#pragma unroll
            for (int r = 0; r < 4; ++r) {
                int row = m0 + wm0 + fm * 16 + lg * 4 + r;
                int col = n0 + wn0 + fn * 16 + l15;
                float v = acc[fm][fn][r];
                if (f32out) ((float*)Cout)[(size_t)row * N + col] = v;
                else        ((u16*)Cout)[(size_t)row * N + col] = f2bf(v);
            }
}

// ---------------- flash attention (causal, GQA), QBLK=64, paired q-tiles ----------------
// V is NOT LDS-staged: total Vt working set = 4 MB, L2-resident (m169 regime);
// PV B-fragments read directly from global (16B/lane contiguous, no swizzle).
// K staging (gload_lds, swizzled) unchanged. LDS 75KB -> 43KB.
__launch_bounds__(256, 3)
__global__ void attn_kernel(const u16* __restrict__ QKV, const u16* __restrict__ Vt,
                            u16* __restrict__ ctx) {
    __shared__ u16 Ks[2][64][128];   // [kv][d], chunk c of row r stored at slot c^(r&15)
    __shared__ u16 Ones[16][64];     // row 0 = 1.0, rows 1..15 = 0
    __shared__ u16 Ps[4][16][72];
    int h = blockIdx.x;
    int pair = blockIdx.y;           // 0..15
    int kvh = h >> 2;
    int tid = threadIdx.x;
    int lane = tid & 63;
    int wave = tid >> 6;
    int l15 = lane & 15, lg = lane >> 4;

    {
        int idx = tid * 4;
        u16 val = (idx < 64) ? (u16)0x3F80 : (u16)0;
        u16* p = &Ones[0][0] + idx;
        p[0] = val; p[1] = val; p[2] = val; p[3] = val;
    }

    int krow = tid >> 4, kj = tid & 15;
    const u16* Kg = QKV + (size_t)krow * DQKV + KOFF + kvh * DHEAD + ((kj ^ krow) * 8);
    const u16* Vb = Vt + (size_t)kvh * DHEAD * T_SEQ;   // this KV-head's [128][T] slab
    u16* Kl = &Ks[0][0][0] + tid * 8;
    const int BUFK = 64 * 128;

#define STAGE(buf, kv0)                                                              \
    {                                                                                \
        _Pragma("unroll")                                                            \
        for (int p = 0; p < 4; ++p)                                                  \
            gload_lds16(Kg + (size_t)((kv0) + p * 16) * DQKV, Kl + (buf) * BUFK + p * 2048); \
    }

    for (int seg = 0; seg < 2; ++seg) {
        int qt = (seg == 0) ? (31 - pair) : pair;   // long tile first
        int q0 = qt * 64;
        int qrow_base = q0 + wave * 16;

        bf16x8 qf[4];
#pragma unroll
        for (int kk = 0; kk < 4; ++kk)
            qf[kk] = *(const bf16x8*)&QKV[(size_t)(qrow_base + l15) * DQKV + h * DHEAD + kk * 32 + lg * 8];

        f32x4 acc_o[8] = {};
        f32x4 acc_l = {0.f, 0.f, 0.f, 0.f};
        float m_run[4];
#pragma unroll
        for (int r = 0; r < 4; ++r) m_run[r] = -1e30f;

        int ntiles = qt + 1;
        __syncthreads();                 // WAR: prior segment's reads of buf0 done
        STAGE(0, 0);

        for (int t = 0; t < ntiles; ++t) {
            int cur = t & 1;
            __syncthreads();             // staged buf[cur] visible
            if (t + 1 < ntiles) STAGE(cur ^ 1, (t + 1) * 64);

            const u16* ksb = &Ks[cur][0][0];
            int kv0 = t * 64;

            f32x4 sacc[4] = {};
#pragma unroll
            for (int nt = 0; nt < 4; ++nt)
#pragma unroll
                for (int kk = 0; kk < 4; ++kk) {
                    int row = nt * 16 + l15;
                    int slot = (kk * 4 + lg) ^ l15;
                    bf16x8 kf = *(const bf16x8*)(ksb + row * 128 + slot * 8);
                    sacc[nt] = __builtin_amdgcn_mfma_f32_16x16x32_bf16(qf[kk], kf, sacc[nt], 0, 0, 0);
                }

            bool diag = (t == ntiles - 1);
#pragma unroll
            for (int r = 0; r < 4; ++r) {
                int qrow = qrow_base + lg * 4 + r;
                float sv[4];
                float pmax = -1e30f;
#pragma unroll
                for (int nt = 0; nt < 4; ++nt) {
                    float s = sacc[nt][r];             // already log2-domain (Q pre-scaled)
                    if (diag && (kv0 + nt * 16 + l15 > qrow)) s = -1e30f;
                    sv[nt] = s;
                    pmax = fmaxf(pmax, s);
                }
#pragma unroll
                for (int m = 1; m < 16; m <<= 1) pmax = fmaxf(pmax, __shfl_xor(pmax, m, 64));
                if (__any(pmax > m_run[r] + 11.5425f)) {   // defer-max, 8*log2e
                    float mnew = fmaxf(m_run[r], pmax);
                    float alpha = __builtin_amdgcn_exp2f(m_run[r] - mnew);
                    m_run[r] = mnew;
#pragma unroll
                    for (int dt = 0; dt < 8; ++dt) acc_o[dt][r] *= alpha;
                    acc_l[r] *= alpha;
                }
#pragma unroll
                for (int nt = 0; nt < 4; ++nt)
                    Ps[wave][lg * 4 + r][nt * 16 + l15] =
                        f2bf_trunc(__builtin_amdgcn_exp2f(sv[nt] - m_run[r]));
            }

            bf16x8 pf[2];
#pragma unroll
            for (int kt = 0; kt < 2; ++kt)
                pf[kt] = *(const bf16x8*)&Ps[wave][l15][kt * 32 + lg * 8];
#pragma unroll
            for (int kt = 0; kt < 2; ++kt) {
                int oslot = (kt * 4 + lg) ^ (l15 & 7);
                bf16x8 of = *(const bf16x8*)(&Ones[0][0] + l15 * 64 + oslot * 8);
                acc_l = __builtin_amdgcn_mfma_f32_16x16x32_bf16(pf[kt], of, acc_l, 0, 0, 0);
            }
#pragma unroll
            for (int dt = 0; dt < 8; ++dt)
#pragma unroll
                for (int kt = 0; kt < 2; ++kt) {
                    // V fragment straight from global (L2-resident Vt [d][t] slab)
                    bf16x8 vf = *(const bf16x8*)&Vb[(size_t)(dt * 16 + l15) * T_SEQ + kv0 + kt * 32 + lg * 8];
                    acc_o[dt] = __builtin_amdgcn_mfma_f32_16x16x32_bf16(pf[kt], vf, acc_o[dt], 0, 0, 0);
                }
        }

#pragma unroll
        for (int r = 0; r < 4; ++r) {
            float lsum = __shfl(acc_l[r], lg * 16, 64);
            float inv = 1.0f / lsum;
#pragma unroll
            for (int dt = 0; dt < 8; ++dt) {
                int row = qrow_base + lg * 4 + r;
                int col = h * DHEAD + dt * 16 + l15;
                ctx[(size_t)row * DMODEL + col] = f2bf(acc_o[dt][r] * inv);
            }
        }
    }
#undef STAGE
}

extern "C" void kernel_launch(void* const* d_in, const int* in_sizes, int n_in,
                              void* d_out, int out_size, void* d_ws, size_t ws_size,
                              hipStream_t stream) {
    const float* resid = (const float*)d_in[0];
    const float* Wq = (const float*)d_in[1];
    const float* Wk = (const float*)d_in[2];
    const float* Wv = (const float*)d_in[3];
    const float* Wo = (const float*)d_in[4];

    char* ws = (char*)d_ws;
    u16* Xb   = (u16*)(ws + 0);           // 2048x4096 bf16 = 16 MiB
    u16* ctx  = (u16*)(ws + 0);           // aliases Xb (dead after QKV GEMM)
    u16* WqT  = (u16*)(ws + 16777216);    // fused B^T rows 0..4095 (32 MiB)
    u16* WkT  = (u16*)(ws + 50331648);    // rows 4096..5119 (8 MiB)
    u16* WvT  = (u16*)(ws + 58720256);    // rows 5120..6143 (8 MiB)
    u16* WoT  = (u16*)(ws + 67108864);    // 32 MiB
    u16* QKV  = (u16*)(ws + 100663296);   // 2048x6144 bf16 = 24 MiB
    u16* Vt   = (u16*)(ws + 125829120);   // 1024x2048 bf16 = 4 MiB
    float* cosT = (float*)(ws + 130023424);
    float* sinT = (float*)(ws + 130547712);

    // fused prep: resid convert + 4 weight transpose-converts + rope tables
    prep_kernel<<<43520, 256, 0, stream>>>(resid, Wq, Wk, Wv, Wo,
                                           Xb, WqT, WkT, WvT, WoT, cosT, sinT);

    // fused QKV projection: 256x192 tiles -> 256 blocks (100% fill), E=4
    gemm8p<256, 192, 4, 2, 4><<<dim3(DQKV / 192, T_SEQ / 256), 512, (256 + 192) * 64 * 2 * 2, stream>>>(
        Xb, WqT, QKV, T_SEQ, DQKV, DMODEL, 0);

    // fused RoPE (Q pre-scaled into log2 domain) + V transpose
    ropevt_kernel<<<22528, 256, 0, stream>>>(QKV, Vt, cosT, sinT);

    // attention: paired q-tiles (y, 31-y) -> 512 balanced blocks; V read from L2
    attn_kernel<<<dim3(NHEADS, 16), 256, 0, stream>>>(QKV, Vt, ctx);

    // output projection: 128x256 tiles -> 256 blocks (100% fill), E=2, f32 out
    gemm8p<128, 256, 2, 4, 2><<<dim3(DMODEL / 256, T_SEQ / 128), 512, (128 + 256) * 64 * 2 * 2, stream>>>(
        ctx, WoT, d_out, T_SEQ, DMODEL, DMODEL, 1);
}

// Round 20
// 306.416 us; speedup vs baseline: 1.2663x; 1.2663x over previous
//
#include <hip/hip_runtime.h>
#include <stdint.h>

#define T_SEQ 2048
#define DMODEL 4096
#define DQKV 6144          // fused Q(4096) + K(1024) + V(1024) output width
#define KOFF 4096          // K column offset in QKV
#define VOFF 5120          // V column offset in QKV
#define DHEAD 128
#define NHEADS 32
#define NKV 8

typedef unsigned short u16;
typedef __attribute__((ext_vector_type(8))) __bf16 bf16x8;
typedef __attribute__((ext_vector_type(4))) float f32x4;

__device__ __forceinline__ u16 f2bf(float f) {
    uint32_t u = __builtin_bit_cast(uint32_t, f);
    u += 0x7FFFu + ((u >> 16) & 1u);
    return (u16)(u >> 16);
}
__device__ __forceinline__ u16 f2bf_trunc(float f) {   // cheap truncation (P-values only)
    return (u16)(__builtin_bit_cast(uint32_t, f) >> 16);
}
__device__ __forceinline__ float bf2f(u16 b) {
    return __builtin_bit_cast(float, (uint32_t)b << 16);
}

__device__ __forceinline__ void gload_lds16(const u16* g, u16* l) {
    __builtin_amdgcn_global_load_lds((const __attribute__((address_space(1))) uint32_t*)g,
                                     (__attribute__((address_space(3))) uint32_t*)l, 16, 0, 0);
}

// =================================================================================
// prep kernel: fuses f32->bf16 convert of resid (cvt), all 4 weight transpose-
// converts (tcvt), and the RoPE cos/sin table build. Flat grid, branch on bid.
// =================================================================================
__global__ void prep_kernel(const float* __restrict__ resid,
                            const float* __restrict__ Wq, const float* __restrict__ Wk,
                            const float* __restrict__ Wv, const float* __restrict__ Wo,
                            u16* __restrict__ Xb,
                            u16* __restrict__ WqT, u16* __restrict__ WkT,
                            u16* __restrict__ WvT, u16* __restrict__ WoT,
                            float* __restrict__ cosT, float* __restrict__ sinT) {
    __shared__ float tile[32][33];
    int bid = blockIdx.x, tid = threadIdx.x;
    if (bid < 2048) {
        int n4 = T_SEQ * DMODEL / 4;
        int i = bid * 256 + tid;
        int stride = 2048 * 256;
        for (; i < n4; i += stride) {
            float4 v = ((const float4*)resid)[i];
            ushort4 o;
            o.x = f2bf(v.x); o.y = f2bf(v.y); o.z = f2bf(v.z); o.w = f2bf(v.w);
            ((ushort4*)Xb)[i] = o;
        }
    } else if (bid < 43008) {
        int b = bid - 2048;
        const float* in; u16* out; int C, s;
        if (b < 16384)      { in = Wq; out = WqT; C = DMODEL; s = b; }
        else if (b < 20480) { in = Wk; out = WkT; C = 1024;   s = b - 16384; }
        else if (b < 24576) { in = Wv; out = WvT; C = 1024;   s = b - 20480; }
        else                { in = Wo; out = WoT; C = DMODEL; s = b - 24576; }
        int ntx = C / 32;
        int c0 = (s % ntx) * 32, r0 = (s / ntx) * 32;
        int tx = tid & 31, ty = tid >> 5;  // 32 x 8
#pragma unroll
        for (int i = 0; i < 32; i += 8)
            tile[ty + i][tx] = in[(size_t)(r0 + ty + i) * C + c0 + tx];
        __syncthreads();
#pragma unroll
        for (int i = 0; i < 32; i += 8)
            out[(size_t)(c0 + ty + i) * DMODEL + r0 + tx] = f2bf(tile[tx][ty + i]);
    } else {
        int local = (bid - 43008) * 256 + tid;
        int t = local >> 6, d = local & 63;
        const float TWO_PI = 6.283185307179586f;
        float fidx = (float)d * (1.0f / 64.0f);
        float freq = (1.0f / TWO_PI) * powf(500000.0f, -fidx);
        const float factor = 32.0f, lo = 1.0f, hi = 4.0f, L0 = 8192.0f;
        float fl = lo / L0, fh = hi / L0;
        float smooth = fminf(fmaxf((L0 * freq - lo) / (hi - lo), 0.0f), 1.0f);
        float fs = (1.0f - smooth) * (freq / factor) + smooth * freq;
        float fr = (freq < fl) ? (freq / factor) : freq;
        if (freq >= fl && freq <= fh) fr = fs;
        float ang = TWO_PI * (float)t * fr;
        cosT[t * 64 + d] = cosf(ang);
        sinT[t * 64 + d] = sinf(ang);
    }
}

// =================================================================================
// ropevt kernel: fuses in-place RoPE on fused QKV (Q heads pre-scaled into log2
// domain, K heads plain) with the V-slice transpose.
// =================================================================================
__global__ void ropevt_kernel(u16* __restrict__ QKV, u16* __restrict__ Vt,
                              const float* __restrict__ cosT, const float* __restrict__ sinT) {
    __shared__ u16 tile[32][33];
    int bid = blockIdx.x, tid = threadIdx.x;
    if (bid < 20480) {
        const float QSCL = 0.08838834764831845f * 1.4426950408889634f;
        int i = bid * 256 + tid;
        int d = i & 63;
        int h = (i >> 6) % 40;
        int t = i / (40 * 64);
        int col = (h < 32) ? (h * 128 + d) : (KOFF + (h - 32) * 128 + d);
        size_t base = (size_t)t * DQKV + col;
        float x0 = bf2f(QKV[base]), x1 = bf2f(QKV[base + 64]);
        float c = cosT[t * 64 + d], s = sinT[t * 64 + d];
        float y0 = x0 * c - x1 * s;
        float y1 = x1 * c + x0 * s;
        if (h < 32) { y0 *= QSCL; y1 *= QSCL; }
        QKV[base] = f2bf(y0);
        QKV[base + 64] = f2bf(y1);
    } else {
        int s = bid - 20480;
        int t0 = (s & 63) * 32, d0 = (s >> 6) * 32;
        int tx = tid & 31, ty = tid >> 5;  // 32 x 8
#pragma unroll
        for (int i = 0; i < 32; i += 8)
            tile[ty + i][tx] = QKV[(size_t)(t0 + ty + i) * DQKV + VOFF + d0 + tx];
        __syncthreads();
#pragma unroll
        for (int i = 0; i < 32; i += 8)
            Vt[(size_t)(d0 + ty + i) * T_SEQ + t0 + tx] = tile[tx][ty + i];
    }
}

// =================================================================================
// GEMM, 3-barrier halves + compiler-counted LDS waits (verified R18): C = A * Bt^T
// =================================================================================
template<int BM, int BN, int WR, int WC, int E>
__launch_bounds__(512, 1)
__global__ void gemm8p(const u16* __restrict__ A, const u16* __restrict__ Bt,
                       void* __restrict__ Cout, int M, int N, int K, int f32out) {
    constexpr int WM = BM / WR, WN = BN / WC;      // per-wave output tile
    constexpr int FM = WM / 16, FN = WN / 16;      // fragments per wave
    constexpr int FMH = FM / 2, FNH = FN / 2;      // fragments per quadrant
    constexpr int NCH = (BM + BN) / 64;            // 64-row stage chunks per K-tile
    constexpr int TILE = (BM + BN) * 64;           // u16 per LDS buffer
    static_assert(E * 64 <= BM, "E-region must stay within A rows");
    extern __shared__ u16 lds[];

    int tid = threadIdx.x;
    int lane = tid & 63, wid = tid >> 6;
    int l15 = lane & 15, lg = lane >> 4;
    int wm0 = (wid / WC) * WM, wn0 = (wid % WC) * WN;
    int m0 = blockIdx.y * BM, n0 = blockIdx.x * BN;
    int rsw = l15 & 7;                             // read-side swizzle = row & 7
    int rl = tid >> 3, cc = tid & 7;
    int scc = cc ^ (rl & 7);                       // source-side pre-swizzle (involution)
    const u16* Ag = A + (size_t)(m0 + rl) * K + scc * 8;
    const u16* Bg = Bt + (size_t)(n0 + rl) * K + scc * 8;
    int niters = K >> 7;

    f32x4 acc[FM][FN] = {};
    bf16x8 aQ0[FMH][2], aQ1[FMH][2];               // A-fragment sets (quad-halves 0/1)
    bf16x8 bQ0[FNH][2], bQ1[FNH][2];               // B-fragment sets

    auto stg = [&](int buf, int t, int clo, int chi) {
#pragma unroll
        for (int c = 0; c < NCH; ++c)
            if (c >= clo && c < chi) {
                const u16* g = (c * 64 < BM) ? (Ag + (size_t)(c * 64) * K + (size_t)t * 64)
                                             : (Bg + (size_t)(c * 64 - BM) * K + (size_t)t * 64);
                gload_lds16(g, lds + buf * TILE + c * 4096 + tid * 8);
            }
    };

#define RDA(buf, qm, DST) { _Pragma("unroll") for (int mi = 0; mi < FMH; ++mi) { \
    int row = wm0 + (qm) * (WM / 2) + mi * 16 + l15; \
    _Pragma("unroll") for (int h = 0; h < 2; ++h) \
        DST[mi][h] = *(const bf16x8*)&lds[(buf) * TILE + row * 64 + (((h * 4 + lg) ^ rsw) * 8)]; } }
#define RDB(buf, qn, DST) { _Pragma("unroll") for (int ni = 0; ni < FNH; ++ni) { \
    int row = wn0 + (qn) * (WN / 2) + ni * 16 + l15; \
    _Pragma("unroll") for (int h = 0; h < 2; ++h) \
        DST[ni][h] = *(const bf16x8*)&lds[(buf) * TILE + BM * 64 + row * 64 + (((h * 4 + lg) ^ rsw) * 8)]; } }
#define MMQ(AR, BR, qm, qn) { _Pragma("unroll") for (int mi = 0; mi < FMH; ++mi) \
    _Pragma("unroll") for (int ni = 0; ni < FNH; ++ni) { \
    acc[(qm)*FMH+mi][(qn)*FNH+ni] = __builtin_amdgcn_mfma_f32_16x16x32_bf16(AR[mi][0], BR[ni][0], acc[(qm)*FMH+mi][(qn)*FNH+ni], 0, 0, 0); \
    acc[(qm)*FMH+mi][(qn)*FNH+ni] = __builtin_amdgcn_mfma_f32_16x16x32_bf16(AR[mi][1], BR[ni][1], acc[(qm)*FMH+mi][(qn)*FNH+ni], 0, 0, 0); } }
#define SB0     __builtin_amdgcn_sched_barrier(0)
#define BAR     __builtin_amdgcn_s_barrier()
#define PRIO1   __builtin_amdgcn_s_setprio(1)
#define PRIO0   __builtin_amdgcn_s_setprio(0)
#define FENCE_E asm volatile("s_waitcnt vmcnt(%0)" :: "i"(E) : "memory")
#define FENCE_0 asm volatile("s_waitcnt vmcnt(0)" ::: "memory")

    // Prologue: tile0 -> buf0 (all chunks), tile1 -> buf1 (first E chunks).
    stg(0, 0, 0, NCH);
    stg(1, 1, 0, E);
    FENCE_E; SB0; BAR;
    RDA(0, 0, aQ0); RDB(0, 0, bQ0);   // tile0 quad0 operands (buf0 complete)

    for (int it = 0; it < niters; ++it) {
        int t0 = 2 * it, t1 = t0 + 1;
        bool last = (it == niters - 1);
        // ---- half 1: tile t0 (buf0); stage t1 rest (buf1) ----
        RDB(0, 1, bQ1); RDA(0, 1, aQ1);
        stg(1, t1, E, NCH);
        SB0; BAR;
        PRIO1; MMQ(aQ0, bQ0, 0, 0); MMQ(aQ0, bQ1, 0, 1); MMQ(aQ1, bQ1, 1, 1); PRIO0;
        SB0; BAR;
        if (!last) stg(0, t0 + 2, 0, E);     // buf0 A: aQ0/aQ1 drained by MFMA waits before BAR above
        SB0;
        PRIO1; MMQ(aQ1, bQ0, 1, 0); PRIO0;
        if (last) { FENCE_0; } else { FENCE_E; }
        SB0; BAR;
        RDA(1, 0, aQ0); RDB(1, 0, bQ0);      // buf1 fully staged (fence+BAR)
        // ---- half 2: tile t1 (buf1); stage t0+2 rest (buf0) ----
        RDB(1, 1, bQ1); RDA(1, 1, aQ1);
        if (!last) stg(0, t0 + 2, E, NCH);   // buf0 B: bQ0/bQ1 drained >=1 BAR ago
        SB0; BAR;
        PRIO1; MMQ(aQ0, bQ0, 0, 0); MMQ(aQ0, bQ1, 0, 1); MMQ(aQ1, bQ1, 1, 1); PRIO0;
        SB0; BAR;
        if (!last) stg(1, t1 + 2, 0, E);     // buf1 A: reads drained before BAR above
        SB0;
        PRIO1; MMQ(aQ1, bQ0, 1, 0); PRIO0;
        if (!last) {
            FENCE_E; SB0; BAR;
            RDA(0, 0, aQ0); RDB(0, 0, bQ0);  // next tile quad0 (buf0 fully staged)
        }
    }
#undef RDA
#undef RDB
#undef MMQ
#undef SB0
#undef BAR
#undef PRIO1
#undef PRIO0
#undef FENCE_E
#undef FENCE_0

#pragma unroll
    for (int fm = 0; fm < FM; ++fm)
#pragma unroll
        for (int fn = 0; fn < FN; ++fn)
#pragma unroll
            for (int r = 0; r < 4; ++r) {
                int row = m0 + wm0 + fm * 16 + lg * 4 + r;
                int col = n0 + wn0 + fn * 16 + l15;
                float v = acc[fm][fn][r];
                if (f32out) ((float*)Cout)[(size_t)row * N + col] = v;
                else        ((u16*)Cout)[(size_t)row * N + col] = f2bf(v);
            }
}

// ---------------- flash attention (causal, GQA), QBLK=64, paired q-tiles ----------------
// (R18 verbatim: K AND V staged via gload_lds, double-buffered — R19 showed inline
// global V reads serialize against MFMA and cost 2.5x.)
__launch_bounds__(256, 3)
__global__ void attn_kernel(const u16* __restrict__ QKV, const u16* __restrict__ Vt,
                            u16* __restrict__ ctx) {
    __shared__ u16 Ks[2][64][128];   // [kv][d], chunk c of row r stored at slot c^(r&15)
    __shared__ u16 Vs[2][128][64];   // [d][kv], chunk c of row r stored at slot c^(r&7)
    __shared__ u16 Ones[16][64];     // row 0 = 1.0, rows 1..15 = 0
    __shared__ u16 Ps[4][16][72];
    int h = blockIdx.x;
    int pair = blockIdx.y;           // 0..15
    int kvh = h >> 2;
    int tid = threadIdx.x;
    int lane = tid & 63;
    int wave = tid >> 6;
    int l15 = lane & 15, lg = lane >> 4;

    {
        int idx = tid * 4;
        u16 val = (idx < 64) ? (u16)0x3F80 : (u16)0;
        u16* p = &Ones[0][0] + idx;
        p[0] = val; p[1] = val; p[2] = val; p[3] = val;
    }

    int krow = tid >> 4, kj = tid & 15;
    int vrow = tid >> 3, vj = tid & 7;
    const u16* Kg = QKV + (size_t)krow * DQKV + KOFF + kvh * DHEAD + ((kj ^ krow) * 8);
    const u16* Vg = Vt + (size_t)(kvh * DHEAD + vrow) * T_SEQ + ((vj ^ (vrow & 7)) * 8);
    u16* Kl = &Ks[0][0][0] + tid * 8;
    u16* Vl = &Vs[0][0][0] + tid * 8;
    const int BUFK = 64 * 128;
    const int BUFV = 128 * 64;

#define STAGE(buf, kv0)                                                              \
    {                                                                                \
        _Pragma("unroll")                                                            \
        for (int p = 0; p < 4; ++p) {                                                \
            gload_lds16(Kg + (size_t)((kv0) + p * 16) * DQKV, Kl + (buf) * BUFK + p * 2048); \
            gload_lds16(Vg + (kv0) + (size_t)(p * 32) * T_SEQ, Vl + (buf) * BUFV + p * 2048); \
        }                                                                            \
    }

    for (int seg = 0; seg < 2; ++seg) {
        int qt = (seg == 0) ? (31 - pair) : pair;   // long tile first
        int q0 = qt * 64;
        int qrow_base = q0 + wave * 16;

        bf16x8 qf[4];
#pragma unroll
        for (int kk = 0; kk < 4; ++kk)
            qf[kk] = *(const bf16x8*)&QKV[(size_t)(qrow_base + l15) * DQKV + h * DHEAD + kk * 32 + lg * 8];

        f32x4 acc_o[8] = {};
        f32x4 acc_l = {0.f, 0.f, 0.f, 0.f};
        float m_run[4];
#pragma unroll
        for (int r = 0; r < 4; ++r) m_run[r] = -1e30f;

        int ntiles = qt + 1;
        __syncthreads();                 // WAR: prior segment's reads of buf0 done
        STAGE(0, 0);

        for (int t = 0; t < ntiles; ++t) {
            int cur = t & 1;
            __syncthreads();             // staged buf[cur] visible
            if (t + 1 < ntiles) STAGE(cur ^ 1, (t + 1) * 64);

            const u16* ksb = &Ks[cur][0][0];
            const u16* vsb = &Vs[cur][0][0];
            int kv0 = t * 64;

            f32x4 sacc[4] = {};
#pragma unroll
            for (int nt = 0; nt < 4; ++nt)
#pragma unroll
                for (int kk = 0; kk < 4; ++kk) {
                    int row = nt * 16 + l15;
                    int slot = (kk * 4 + lg) ^ l15;
                    bf16x8 kf = *(const bf16x8*)(ksb + row * 128 + slot * 8);
                    sacc[nt] = __builtin_amdgcn_mfma_f32_16x16x32_bf16(qf[kk], kf, sacc[nt], 0, 0, 0);
                }

            bool diag = (t == ntiles - 1);
#pragma unroll
            for (int r = 0; r < 4; ++r) {
                int qrow = qrow_base + lg * 4 + r;
                float sv[4];
                float pmax = -1e30f;
#pragma unroll
                for (int nt = 0; nt < 4; ++nt) {
                    float s = sacc[nt][r];             // already log2-domain (Q pre-scaled)
                    if (diag && (kv0 + nt * 16 + l15 > qrow)) s = -1e30f;
                    sv[nt] = s;
                    pmax = fmaxf(pmax, s);
                }
#pragma unroll
                for (int m = 1; m < 16; m <<= 1) pmax = fmaxf(pmax, __shfl_xor(pmax, m, 64));
                if (__any(pmax > m_run[r] + 11.5425f)) {   // defer-max, 8*log2e
                    float mnew = fmaxf(m_run[r], pmax);
                    float alpha = __builtin_amdgcn_exp2f(m_run[r] - mnew);
                    m_run[r] = mnew;
#pragma unroll
                    for (int dt = 0; dt < 8; ++dt) acc_o[dt][r] *= alpha;
                    acc_l[r] *= alpha;
                }
#pragma unroll
                for (int nt = 0; nt < 4; ++nt)
                    Ps[wave][lg * 4 + r][nt * 16 + l15] =
                        f2bf_trunc(__builtin_amdgcn_exp2f(sv[nt] - m_run[r]));
            }

            bf16x8 pf[2];
#pragma unroll
            for (int kt = 0; kt < 2; ++kt)
                pf[kt] = *(const bf16x8*)&Ps[wave][l15][kt * 32 + lg * 8];
#pragma unroll
            for (int kt = 0; kt < 2; ++kt) {
                int oslot = (kt * 4 + lg) ^ (l15 & 7);
                bf16x8 of = *(const bf16x8*)(&Ones[0][0] + l15 * 64 + oslot * 8);
                acc_l = __builtin_amdgcn_mfma_f32_16x16x32_bf16(pf[kt], of, acc_l, 0, 0, 0);
            }
#pragma unroll
            for (int dt = 0; dt < 8; ++dt)
#pragma unroll
                for (int kt = 0; kt < 2; ++kt) {
                    int vr = dt * 16 + l15;
                    int slot = (kt * 4 + lg) ^ (l15 & 7);
                    bf16x8 vf = *(const bf16x8*)(vsb + vr * 64 + slot * 8);
                    acc_o[dt] = __builtin_amdgcn_mfma_f32_16x16x32_bf16(pf[kt], vf, acc_o[dt], 0, 0, 0);
                }
        }

#pragma unroll
        for (int r = 0; r < 4; ++r) {
            float lsum = __shfl(acc_l[r], lg * 16, 64);
            float inv = 1.0f / lsum;
#pragma unroll
            for (int dt = 0; dt < 8; ++dt) {
                int row = qrow_base + lg * 4 + r;
                int col = h * DHEAD + dt * 16 + l15;
                ctx[(size_t)row * DMODEL + col] = f2bf(acc_o[dt][r] * inv);
            }
        }
    }
#undef STAGE
}

extern "C" void kernel_launch(void* const* d_in, const int* in_sizes, int n_in,
                              void* d_out, int out_size, void* d_ws, size_t ws_size,
                              hipStream_t stream) {
    const float* resid = (const float*)d_in[0];
    const float* Wq = (const float*)d_in[1];
    const float* Wk = (const float*)d_in[2];
    const float* Wv = (const float*)d_in[3];
    const float* Wo = (const float*)d_in[4];

    char* ws = (char*)d_ws;
    u16* Xb   = (u16*)(ws + 0);           // 2048x4096 bf16 = 16 MiB
    u16* ctx  = (u16*)(ws + 0);           // aliases Xb (dead after QKV GEMM)
    u16* WqT  = (u16*)(ws + 16777216);    // fused B^T rows 0..4095 (32 MiB)
    u16* WkT  = (u16*)(ws + 50331648);    // rows 4096..5119 (8 MiB)
    u16* WvT  = (u16*)(ws + 58720256);    // rows 5120..6143 (8 MiB)
    u16* WoT  = (u16*)(ws + 67108864);    // 32 MiB
    u16* QKV  = (u16*)(ws + 100663296);   // 2048x6144 bf16 = 24 MiB
    u16* Vt   = (u16*)(ws + 125829120);   // 1024x2048 bf16 = 4 MiB
    float* cosT = (float*)(ws + 130023424);
    float* sinT = (float*)(ws + 130547712);

    // fused prep: resid convert + 4 weight transpose-converts + rope tables
    prep_kernel<<<43520, 256, 0, stream>>>(resid, Wq, Wk, Wv, Wo,
                                           Xb, WqT, WkT, WvT, WoT, cosT, sinT);

    // fused QKV projection: 256x192 tiles -> 256 blocks (100% fill), E=4
    gemm8p<256, 192, 4, 2, 4><<<dim3(DQKV / 192, T_SEQ / 256), 512, (256 + 192) * 64 * 2 * 2, stream>>>(
        Xb, WqT, QKV, T_SEQ, DQKV, DMODEL, 0);

    // fused RoPE (Q pre-scaled into log2 domain) + V transpose
    ropevt_kernel<<<22528, 256, 0, stream>>>(QKV, Vt, cosT, sinT);

    // attention: paired q-tiles (y, 31-y) -> 512 balanced blocks, K+V LDS-staged
    attn_kernel<<<dim3(NHEADS, 16), 256, 0, stream>>>(QKV, Vt, ctx);

    // output projection: 128x256 tiles -> 256 blocks (100% fill), E=2, f32 out
    gemm8p<128, 256, 2, 4, 2><<<dim3(DMODEL / 256, T_SEQ / 128), 512, (128 + 256) * 64 * 2 * 2, stream>>>(
        ctx, WoT, d_out, T_SEQ, DMODEL, DMODEL, 1);
}